// Round 5
// baseline (622.669 us; speedup 1.0000x reference)
//
#include <hip/hip_runtime.h>

#define NROWS    262144   // 16 * 16384
#define DIMS     64
#define KCODES   512
#define MTILE    32       // rows per block
#define RPW      4        // rows per wave  (>=5 breaks the 64-VGPR / 8-waves-per-SIMD regime)
#define CHUNK    256      // epilogue col-half width (col->lane ownership, frozen)
#define NCHUNK   2        // col halves per lane (8 cols/lane total, frozen)
#define D_PER    16       // dims per LDS stage  -> 16*512*4 = 32 KB
#define D_CHUNKS 4        // 64 / 16
#define NTHREADS 512

// ---------------------------------------------------------------------------
// prep: embedT[k][d] = embed[d][k]; enorm[k] = sum_d embed[d][k]^2 (numpy
// pairwise-8 order); zero the likelihood accumulator.
// grid <<<512, 64>>> : block = one code k, lane = d.
// ---------------------------------------------------------------------------
__global__ void prep_kernel(const float* __restrict__ embed,
                            float* __restrict__ embedT,
                            float* __restrict__ enorm,
                            float* __restrict__ lik) {
    int k = blockIdx.x;
    int d = threadIdx.x;
    float v = embed[d * KCODES + k];
    embedT[k * DIMS + d] = v;
    float sq = __fmul_rn(v, v);
    // numpy pairwise: r_j = sq_j + sq_{j+8} + ... (sequential), j = d & 7
    int j = d & 7;
    float r = __shfl(sq, j, 64);
#pragma unroll
    for (int i = 1; i < 8; ++i)
        r = __fadd_rn(r, __shfl(sq, j + 8 * i, 64));
    // combine ((r0+r1)+(r2+r3)) + ((r4+r5)+(r6+r7)) via xor tree (bitwise exact)
    float t;
    t = __shfl_xor(r, 1, 64); r = __fadd_rn(r, t);
    t = __shfl_xor(r, 2, 64); r = __fadd_rn(r, t);
    t = __shfl_xor(r, 4, 64); r = __fadd_rn(r, t);
    if (d == 0) { enorm[k] = r; lik[k] = 0.0f; }
}

// ---------------------------------------------------------------------------
// main: fused GEMM + softmax + argmax + hard-gather + likelihood partials.
// grid <<<8192, 512>>>. Block: 32 rows x 512 cols.
// Thread (cg = tid&63, rg = tid>>6): 4 rows x 8 cols -> acc[2][4][4] = 32
// VGPRs. Wave = 4 full rows (in-wave softmax).
//
// ROUND-5: round-3 structure (best: 524 us, VGPR 40, occ 68%) with the d2
// inner loop FULLY unrolled (8 dim-pairs per stage) and one x base pointer
// hoisted per row per stage. Rationale: round-3 counters show all pipes
// half-busy (VALU 52%, DS ~40%, HBM 2.4%) -> issue/latency-bound; the
// unroll-2 window recomputed LDS/global addresses every 2 dim-pairs (~3 VALU
// per ds_read + mul/add per x-load) and limited load MLP. Full unroll folds
// every offset into compile-time immediates (ds_read_b128 offset:N /
// global_load offset:N) and gives the scheduler a 32-load window. fmaf chains
// per accumulator are untouched -> bit-identical. Round-4 lesson: VGPR must
// stay <=64 (waves/SIMD halve past 64; occ collapsed 68->24 at VGPR=80), so
// RPW stays 4 and no launch-bounds games.
// ---------------------------------------------------------------------------
__launch_bounds__(NTHREADS)
__global__ void main_kernel(const float* __restrict__ x,
                            const float* __restrict__ embed,
                            const float* __restrict__ sigma,
                            const float* __restrict__ embedT,
                            const float* __restrict__ enorm,
                            float* __restrict__ lik,
                            float* __restrict__ out) {
    __shared__ float e_lds[D_PER * KCODES];   // 32 KB

    const int tid = threadIdx.x;
    const int cg  = tid & 63;        // col group (4 cols per half)
    const int rg  = tid >> 6;        // row group (4 rows), == wave id
    const int rowbase = blockIdx.x * MTILE + rg * RPW;

    const float sigma_v = sigma[0];

    float acc[NCHUNK][RPW][4];
#pragma unroll
    for (int c = 0; c < NCHUNK; ++c)
#pragma unroll
        for (int r = 0; r < RPW; ++r)
#pragma unroll
            for (int q = 0; q < 4; ++q) acc[c][r][q] = 0.0f;

    const float4* __restrict__ eg4 = reinterpret_cast<const float4*>(embed);
    float4* e_lds4 = reinterpret_cast<float4*>(e_lds);

    // per-row x base pointers (float2 granularity); advance by 8 pairs/stage
    const float2* __restrict__ xrow[RPW];
#pragma unroll
    for (int r = 0; r < RPW; ++r)
        xrow[r] = reinterpret_cast<const float2*>(x) +
                  (size_t)(rowbase + r) * (DIMS / 2);

    for (int dc = 0; dc < D_CHUNKS; ++dc) {
        __syncthreads();   // protect previous stage's readers
        // stage e[dc*16 .. dc*16+15][0..511]: perfectly linear float4 copy
#pragma unroll
        for (int i = 0; i < 4; ++i) {
            int f4 = tid + i * NTHREADS;          // 0..2047
            e_lds4[f4] = eg4[dc * (D_PER * KCODES / 4) + f4];
        }
        __syncthreads();

        const float4* e4 = reinterpret_cast<const float4*>(e_lds);
        const int dbase = dc * (D_PER / 2);       // global dim-pair base
#pragma unroll
        for (int d2 = 0; d2 < D_PER / 2; ++d2) {  // FULL unroll: 8 dim pairs
            // e rows for dims (2*d2, 2*d2+1), both col halves (4 cols each);
            // d2 is compile-time -> ds_read_b128 with immediate offsets
            float4 e0a = e4[(2 * d2 + 0) * 128 +  0 + cg];   // dim lo, half 0
            float4 e1a = e4[(2 * d2 + 1) * 128 +  0 + cg];   // dim hi, half 0
            float4 e0b = e4[(2 * d2 + 0) * 128 + 64 + cg];   // dim lo, half 1
            float4 e1b = e4[(2 * d2 + 1) * 128 + 64 + cg];   // dim hi, half 1
#pragma unroll
            for (int r = 0; r < RPW; ++r) {
                float2 xv = xrow[r][dbase + d2];  // imm-offset global load
                // ascending-d sequential fma chain per (r,col) — bit-exact
                acc[0][r][0] = fmaf(xv.x, e0a.x, acc[0][r][0]);
                acc[0][r][1] = fmaf(xv.x, e0a.y, acc[0][r][1]);
                acc[0][r][2] = fmaf(xv.x, e0a.z, acc[0][r][2]);
                acc[0][r][3] = fmaf(xv.x, e0a.w, acc[0][r][3]);
                acc[0][r][0] = fmaf(xv.y, e1a.x, acc[0][r][0]);
                acc[0][r][1] = fmaf(xv.y, e1a.y, acc[0][r][1]);
                acc[0][r][2] = fmaf(xv.y, e1a.z, acc[0][r][2]);
                acc[0][r][3] = fmaf(xv.y, e1a.w, acc[0][r][3]);
                acc[1][r][0] = fmaf(xv.x, e0b.x, acc[1][r][0]);
                acc[1][r][1] = fmaf(xv.x, e0b.y, acc[1][r][1]);
                acc[1][r][2] = fmaf(xv.x, e0b.z, acc[1][r][2]);
                acc[1][r][3] = fmaf(xv.x, e0b.w, acc[1][r][3]);
                acc[1][r][0] = fmaf(xv.y, e1b.x, acc[1][r][0]);
                acc[1][r][1] = fmaf(xv.y, e1b.y, acc[1][r][1]);
                acc[1][r][2] = fmaf(xv.y, e1b.z, acc[1][r][2]);
                acc[1][r][3] = fmaf(xv.y, e1b.w, acc[1][r][3]);
            }
        }
    }

    // ---- xnorm for the wave's 4 rows, numpy pairwise-8 order ----
    // lane cg = r_l*8 + j_l computes partial r_{j_l} of row (r_l & 3); the
    // upper 32 lanes duplicate rows 0-3 (keeps the 8-lane xor tree bit-exact
    // and avoids reading rows outside this wave's ownership).
    const int r_l = (cg >> 3) & 3;
    const int j_l = cg & 7;
    float xr;
    {
        const float* xp = x + (size_t)(rowbase + r_l) * DIMS + j_l;
        float v0 = xp[0];
        float s = __fmul_rn(v0, v0);
#pragma unroll
        for (int i = 1; i < 8; ++i) {
            float v = xp[8 * i];
            s = __fadd_rn(s, __fmul_rn(v, v));
        }
        xr = s;
    }
    {
        float t;
        t = __shfl_xor(xr, 1, 64); xr = __fadd_rn(xr, t);
        t = __shfl_xor(xr, 2, 64); xr = __fadd_rn(xr, t);
        t = __shfl_xor(xr, 4, 64); xr = __fadd_rn(xr, t);
    }
    // lane r*8+j now holds xnorm of row r (r = 0..3)

    // enorm for this thread's 8 cols
    float en[NCHUNK][4];
#pragma unroll
    for (int c = 0; c < NCHUNK; ++c)
#pragma unroll
        for (int q = 0; q < 4; ++q)
            en[c][q] = enorm[c * CHUNK + cg * 4 + q];

    float likpart[NCHUNK][4];
#pragma unroll
    for (int c = 0; c < NCHUNK; ++c)
#pragma unroll
        for (int q = 0; q < 4; ++q) likpart[c][q] = 0.0f;

#pragma unroll
    for (int r = 0; r < RPW; ++r) {
        float xn = __shfl(xr, r * 8, 64);
        // z = -sigma * ((xnorm - 2*dot) + enorm), np-assembly order.
        // IN-PLACE: z overwrites acc[c][r][q] (dot is dead afterwards).
        float m = -INFINITY;
#pragma unroll
        for (int c = 0; c < NCHUNK; ++c)
#pragma unroll
            for (int q = 0; q < 4; ++q) {
                float dot  = acc[c][r][q];
                float td   = __fsub_rn(xn, __fmul_rn(2.0f, dot));
                float dist = __fadd_rn(td, en[c][q]);
                float zz   = __fmul_rn(-sigma_v, dist);
                acc[c][r][q] = zz;
                m = fmaxf(m, zz);
            }
#pragma unroll
        for (int mask = 1; mask < 64; mask <<= 1)
            m = fmaxf(m, __shfl_xor(m, mask, 64));

        // ev overwrites z in place
        float s = 0.0f;
        float bv = -1.0f;
        int   bc = KCODES;
#pragma unroll
        for (int c = 0; c < NCHUNK; ++c)
#pragma unroll
            for (int q = 0; q < 4; ++q) {
                float ee = expf(__fsub_rn(acc[c][r][q], m));
                acc[c][r][q] = ee;
                s += ee;
                int col = c * CHUNK + cg * 4 + q;
                if (ee > bv) { bv = ee; bc = col; }   // first-index tiebreak
            }
#pragma unroll
        for (int mask = 1; mask < 64; mask <<= 1)
            s += __shfl_xor(s, mask, 64);
#pragma unroll
        for (int mask = 1; mask < 64; mask <<= 1) {
            float ov = __shfl_xor(bv, mask, 64);
            int   oc = __shfl_xor(bc, mask, 64);
            if (ov > bv || (ov == bv && oc < bc)) { bv = ov; bc = oc; }
        }

        float invS = 1.0f / s;
#pragma unroll
        for (int c = 0; c < NCHUNK; ++c)
#pragma unroll
            for (int q = 0; q < 4; ++q)
                likpart[c][q] = fmaf(acc[c][r][q], invS, likpart[c][q]);

        // hard-gather write: quantize[row][cg] = embedT[bc][cg]
        // nontemporal: avoid write-allocate RFO on the 64 MB output
        int row = rowbase + r;
        __builtin_nontemporal_store(embedT[bc * DIMS + cg],
                                    &out[(size_t)row * DIMS + cg]);
    }

    // ---- block-level likelihood reduction (reuse e_lds) ----
    float* red = e_lds;
    __syncthreads();
    red[tid] = 0.0f;
    __syncthreads();
#pragma unroll
    for (int c = 0; c < NCHUNK; ++c)
#pragma unroll
        for (int q = 0; q < 4; ++q)
            atomicAdd(&red[c * CHUNK + cg * 4 + q], likpart[c][q]);
    __syncthreads();
    atomicAdd(&lik[tid], red[tid]);
}

// ---------------------------------------------------------------------------
// finish: likelihoods = lik_sum / N; quant_loss = 0.25 * mean(p*(log p - log(l+eps)))
// ---------------------------------------------------------------------------
__global__ void finish_kernel(const float* __restrict__ lik,
                              float* __restrict__ out) {
    int tid = threadIdx.x;   // 512 threads
    float l = lik[tid] / 262144.0f;     // exact: divide by 2^18
    out[16777217 + tid] = l;
    const float p = 1.0f / 512.0f;
    float term = __fmul_rn(p, __fsub_rn(logf(p), logf(l + 1e-10f)));
#pragma unroll
    for (int mask = 1; mask < 64; mask <<= 1)
        term += __shfl_xor(term, mask, 64);
    __shared__ float ws[8];
    if ((tid & 63) == 0) ws[tid >> 6] = term;
    __syncthreads();
    if (tid == 0) {
        float ssum = 0.0f;
        for (int i = 0; i < 8; ++i) ssum += ws[i];
        out[16777216] = 0.25f * (ssum / 512.0f);
    }
}

extern "C" void kernel_launch(void* const* d_in, const int* in_sizes, int n_in,
                              void* d_out, int out_size, void* d_ws, size_t ws_size,
                              hipStream_t stream) {
    const float* x     = (const float*)d_in[0];
    const float* embed = (const float*)d_in[1];
    const float* sigma = (const float*)d_in[2];
    float* out = (float*)d_out;
    float* ws  = (float*)d_ws;

    float* embedT = ws;             // 512*64 = 32768 floats
    float* enorm  = ws + 32768;     // 512 floats
    float* lik    = ws + 33280;     // 512 floats

    prep_kernel<<<KCODES, DIMS, 0, stream>>>(embed, embedT, enorm, lik);
    main_kernel<<<NROWS / MTILE, NTHREADS, 0, stream>>>(x, embed, sigma,
                                                        embedT, enorm, lik, out);
    finish_kernel<<<1, NTHREADS, 0, stream>>>(lik, out);
}

// Round 6
// 586.964 us; speedup vs baseline: 1.0608x; 1.0608x over previous
//
#include <hip/hip_runtime.h>

#define NROWS    262144   // 16 * 16384
#define DIMS     64
#define KCODES   512
#define MTILE    32       // rows per block
#define RPW      4        // rows per wave (>=5 breaks the <=64-VGPR regime; R4: occ 68->24)
#define CHUNK    256      // epilogue col-half width (col->lane ownership, frozen)
#define NCHUNK   2        // col halves per lane (8 cols/lane total, frozen)
#define D_PER    8        // dims per LDS stage -> 8*512*4 = 16 KB per buffer
#define D_CHUNKS 8        // 64 / 8
#define NTHREADS 512

// ---------------------------------------------------------------------------
// prep: embedT[k][d] = embed[d][k]; enorm[k] = sum_d embed[d][k]^2 (numpy
// pairwise-8 order); zero the likelihood accumulator.
// grid <<<512, 64>>> : block = one code k, lane = d.
// ---------------------------------------------------------------------------
__global__ void prep_kernel(const float* __restrict__ embed,
                            float* __restrict__ embedT,
                            float* __restrict__ enorm,
                            float* __restrict__ lik) {
    int k = blockIdx.x;
    int d = threadIdx.x;
    float v = embed[d * KCODES + k];
    embedT[k * DIMS + d] = v;
    float sq = __fmul_rn(v, v);
    // numpy pairwise: r_j = sq_j + sq_{j+8} + ... (sequential), j = d & 7
    int j = d & 7;
    float r = __shfl(sq, j, 64);
#pragma unroll
    for (int i = 1; i < 8; ++i)
        r = __fadd_rn(r, __shfl(sq, j + 8 * i, 64));
    // combine ((r0+r1)+(r2+r3)) + ((r4+r5)+(r6+r7)) via xor tree (bitwise exact)
    float t;
    t = __shfl_xor(r, 1, 64); r = __fadd_rn(r, t);
    t = __shfl_xor(r, 2, 64); r = __fadd_rn(r, t);
    t = __shfl_xor(r, 4, 64); r = __fadd_rn(r, t);
    if (d == 0) { enorm[k] = r; lik[k] = 0.0f; }
}

// ---------------------------------------------------------------------------
// main: fused GEMM + softmax + argmax + hard-gather + likelihood partials.
// grid <<<8192, 512>>>. Block: 32 rows x 512 cols.
// Thread (cg = tid&63, rg = tid>>6): 4 rows x 8 cols -> acc[2][4][4] = 32
// VGPRs. Wave = 4 full rows (in-wave softmax).
//
// ROUND-6: double-buffered e staging via __builtin_amdgcn_global_load_lds
// (T3-lite 2-phase pipeline). R3 (best, 524us) ran staging synchronously:
// barrier -> global->VGPR -> vmcnt -> ds_write -> barrier -> compute, exposing
// the full HBM/L2 latency 4x per block with 2 barriers per stage (VALU idle
// 48% with all pipes half-busy). Now: while computing stage t from buf[t&1],
// stage t+1 is fired into buf[(t+1)&1] with global_load_lds (no VGPR
// round-trip, no ds_write issue); __syncthreads at stage end drains vmcnt ->
// staged data ready. One barrier per stage. D_PER 16->8 keeps total LDS at
// 2x16=32 KB -> still 4 blocks/CU. LDS dest satisfies the wave-uniform-base +
// lane*16 rule: f4 = tid + i*512 -> per (wave,i) base + lane*16, linear.
// fmaf chains, lane->col ownership, reduction trees untouched -> bit-exact.
// R5 lesson: full unroll / pointer arrays regress (compiler already folds
// addresses; load convoys hurt) -> inner loop kept in R3 form, unroll 2.
// ---------------------------------------------------------------------------
__launch_bounds__(NTHREADS)
__global__ void main_kernel(const float* __restrict__ x,
                            const float* __restrict__ embed,
                            const float* __restrict__ sigma,
                            const float* __restrict__ embedT,
                            const float* __restrict__ enorm,
                            float* __restrict__ lik,
                            float* __restrict__ out) {
    __shared__ float e_lds[2 * D_PER * KCODES];   // 2 x 16 KB

    const int tid = threadIdx.x;
    const int cg  = tid & 63;        // col group (4 cols per half)
    const int rg  = tid >> 6;        // row group (4 rows), == wave id
    const int rowbase = blockIdx.x * MTILE + rg * RPW;

    const float sigma_v = sigma[0];

    float acc[NCHUNK][RPW][4];
#pragma unroll
    for (int c = 0; c < NCHUNK; ++c)
#pragma unroll
        for (int r = 0; r < RPW; ++r)
#pragma unroll
            for (int q = 0; q < 4; ++q) acc[c][r][q] = 0.0f;

    const float2* __restrict__ x2  = reinterpret_cast<const float2*>(x);
    const float4* __restrict__ eg4 = reinterpret_cast<const float4*>(embed);
    float4* e4all = reinterpret_cast<float4*>(e_lds);

    // ---- prologue: stage chunk 0 into buffer 0 (async, then barrier) ----
#pragma unroll
    for (int i = 0; i < 2; ++i) {
        int f4 = tid + i * NTHREADS;              // 0..1023
        __builtin_amdgcn_global_load_lds(
            (const __attribute__((address_space(1))) void*)(eg4 + f4),
            (__attribute__((address_space(3))) void*)(e4all + f4),
            16, 0, 0);
    }
    __syncthreads();   // drains vmcnt -> buf0 ready

    for (int dc = 0; dc < D_CHUNKS; ++dc) {
        // fire staging of chunk dc+1 into the other buffer (no wait here)
        if (dc + 1 < D_CHUNKS) {
            const int nb = (dc + 1) & 1;
#pragma unroll
            for (int i = 0; i < 2; ++i) {
                int f4 = tid + i * NTHREADS;
                __builtin_amdgcn_global_load_lds(
                    (const __attribute__((address_space(1))) void*)
                        (eg4 + (dc + 1) * (D_PER * KCODES / 4) + f4),
                    (__attribute__((address_space(3))) void*)
                        (e4all + nb * (D_PER * KCODES / 4) + f4),
                    16, 0, 0);
            }
        }

        // compute stage dc from buf[dc&1]
        const float4* e4 = e4all + (dc & 1) * (D_PER * KCODES / 4);
        const int dbase = dc * (D_PER / 2);       // global dim-pair base
#pragma unroll 2
        for (int d2 = 0; d2 < D_PER / 2; ++d2) {  // 4 dim pairs per stage
            float4 e0a = e4[(2 * d2 + 0) * 128 +  0 + cg];   // dim lo, half 0
            float4 e1a = e4[(2 * d2 + 1) * 128 +  0 + cg];   // dim hi, half 0
            float4 e0b = e4[(2 * d2 + 0) * 128 + 64 + cg];   // dim lo, half 1
            float4 e1b = e4[(2 * d2 + 1) * 128 + 64 + cg];   // dim hi, half 1
            int d2g = dbase + d2;                            // global dim-pair
#pragma unroll
            for (int r = 0; r < RPW; ++r) {
                float2 xv = x2[(size_t)(rowbase + r) * 32 + d2g];
                // ascending-d sequential fma chain per (r,col) — bit-exact
                acc[0][r][0] = fmaf(xv.x, e0a.x, acc[0][r][0]);
                acc[0][r][1] = fmaf(xv.x, e0a.y, acc[0][r][1]);
                acc[0][r][2] = fmaf(xv.x, e0a.z, acc[0][r][2]);
                acc[0][r][3] = fmaf(xv.x, e0a.w, acc[0][r][3]);
                acc[0][r][0] = fmaf(xv.y, e1a.x, acc[0][r][0]);
                acc[0][r][1] = fmaf(xv.y, e1a.y, acc[0][r][1]);
                acc[0][r][2] = fmaf(xv.y, e1a.z, acc[0][r][2]);
                acc[0][r][3] = fmaf(xv.y, e1a.w, acc[0][r][3]);
                acc[1][r][0] = fmaf(xv.x, e0b.x, acc[1][r][0]);
                acc[1][r][1] = fmaf(xv.x, e0b.y, acc[1][r][1]);
                acc[1][r][2] = fmaf(xv.x, e0b.z, acc[1][r][2]);
                acc[1][r][3] = fmaf(xv.x, e0b.w, acc[1][r][3]);
                acc[1][r][0] = fmaf(xv.y, e1b.x, acc[1][r][0]);
                acc[1][r][1] = fmaf(xv.y, e1b.y, acc[1][r][1]);
                acc[1][r][2] = fmaf(xv.y, e1b.z, acc[1][r][2]);
                acc[1][r][3] = fmaf(xv.y, e1b.w, acc[1][r][3]);
            }
        }
        // one barrier per stage: (a) drains vmcnt so next buf is ready for
        // everyone, (b) all readers of current buf done before it's restaged.
        __syncthreads();
    }

    // ---- xnorm for the wave's 4 rows, numpy pairwise-8 order ----
    // lane cg = r_l*8 + j_l computes partial r_{j_l} of row (r_l & 3); the
    // upper 32 lanes duplicate rows 0-3 (keeps the 8-lane xor tree bit-exact
    // and avoids reading rows outside this wave's ownership).
    const int r_l = (cg >> 3) & 3;
    const int j_l = cg & 7;
    float xr;
    {
        const float* xp = x + (size_t)(rowbase + r_l) * DIMS + j_l;
        float v0 = xp[0];
        float s = __fmul_rn(v0, v0);
#pragma unroll
        for (int i = 1; i < 8; ++i) {
            float v = xp[8 * i];
            s = __fadd_rn(s, __fmul_rn(v, v));
        }
        xr = s;
    }
    {
        float t;
        t = __shfl_xor(xr, 1, 64); xr = __fadd_rn(xr, t);
        t = __shfl_xor(xr, 2, 64); xr = __fadd_rn(xr, t);
        t = __shfl_xor(xr, 4, 64); xr = __fadd_rn(xr, t);
    }
    // lane r*8+j now holds xnorm of row r (r = 0..3)

    // enorm for this thread's 8 cols
    float en[NCHUNK][4];
#pragma unroll
    for (int c = 0; c < NCHUNK; ++c)
#pragma unroll
        for (int q = 0; q < 4; ++q)
            en[c][q] = enorm[c * CHUNK + cg * 4 + q];

    float likpart[NCHUNK][4];
#pragma unroll
    for (int c = 0; c < NCHUNK; ++c)
#pragma unroll
        for (int q = 0; q < 4; ++q) likpart[c][q] = 0.0f;

#pragma unroll
    for (int r = 0; r < RPW; ++r) {
        float xn = __shfl(xr, r * 8, 64);
        // z = -sigma * ((xnorm - 2*dot) + enorm), np-assembly order.
        // IN-PLACE: z overwrites acc[c][r][q] (dot is dead afterwards).
        float m = -INFINITY;
#pragma unroll
        for (int c = 0; c < NCHUNK; ++c)
#pragma unroll
            for (int q = 0; q < 4; ++q) {
                float dot  = acc[c][r][q];
                float td   = __fsub_rn(xn, __fmul_rn(2.0f, dot));
                float dist = __fadd_rn(td, en[c][q]);
                float zz   = __fmul_rn(-sigma_v, dist);
                acc[c][r][q] = zz;
                m = fmaxf(m, zz);
            }
#pragma unroll
        for (int mask = 1; mask < 64; mask <<= 1)
            m = fmaxf(m, __shfl_xor(m, mask, 64));

        // ev overwrites z in place
        float s = 0.0f;
        float bv = -1.0f;
        int   bc = KCODES;
#pragma unroll
        for (int c = 0; c < NCHUNK; ++c)
#pragma unroll
            for (int q = 0; q < 4; ++q) {
                float ee = expf(__fsub_rn(acc[c][r][q], m));
                acc[c][r][q] = ee;
                s += ee;
                int col = c * CHUNK + cg * 4 + q;
                if (ee > bv) { bv = ee; bc = col; }   // first-index tiebreak
            }
#pragma unroll
        for (int mask = 1; mask < 64; mask <<= 1)
            s += __shfl_xor(s, mask, 64);
#pragma unroll
        for (int mask = 1; mask < 64; mask <<= 1) {
            float ov = __shfl_xor(bv, mask, 64);
            int   oc = __shfl_xor(bc, mask, 64);
            if (ov > bv || (ov == bv && oc < bc)) { bv = ov; bc = oc; }
        }

        float invS = 1.0f / s;
#pragma unroll
        for (int c = 0; c < NCHUNK; ++c)
#pragma unroll
            for (int q = 0; q < 4; ++q)
                likpart[c][q] = fmaf(acc[c][r][q], invS, likpart[c][q]);

        // hard-gather write: quantize[row][cg] = embedT[bc][cg]
        // nontemporal: avoid write-allocate RFO on the 64 MB output
        int row = rowbase + r;
        __builtin_nontemporal_store(embedT[bc * DIMS + cg],
                                    &out[(size_t)row * DIMS + cg]);
    }

    // ---- block-level likelihood reduction (reuse e_lds) ----
    float* red = e_lds;
    __syncthreads();
    red[tid] = 0.0f;
    __syncthreads();
#pragma unroll
    for (int c = 0; c < NCHUNK; ++c)
#pragma unroll
        for (int q = 0; q < 4; ++q)
            atomicAdd(&red[c * CHUNK + cg * 4 + q], likpart[c][q]);
    __syncthreads();
    atomicAdd(&lik[tid], red[tid]);
}

// ---------------------------------------------------------------------------
// finish: likelihoods = lik_sum / N; quant_loss = 0.25 * mean(p*(log p - log(l+eps)))
// ---------------------------------------------------------------------------
__global__ void finish_kernel(const float* __restrict__ lik,
                              float* __restrict__ out) {
    int tid = threadIdx.x;   // 512 threads
    float l = lik[tid] / 262144.0f;     // exact: divide by 2^18
    out[16777217 + tid] = l;
    const float p = 1.0f / 512.0f;
    float term = __fmul_rn(p, __fsub_rn(logf(p), logf(l + 1e-10f)));
#pragma unroll
    for (int mask = 1; mask < 64; mask <<= 1)
        term += __shfl_xor(term, mask, 64);
    __shared__ float ws[8];
    if ((tid & 63) == 0) ws[tid >> 6] = term;
    __syncthreads();
    if (tid == 0) {
        float ssum = 0.0f;
        for (int i = 0; i < 8; ++i) ssum += ws[i];
        out[16777216] = 0.25f * (ssum / 512.0f);
    }
}

extern "C" void kernel_launch(void* const* d_in, const int* in_sizes, int n_in,
                              void* d_out, int out_size, void* d_ws, size_t ws_size,
                              hipStream_t stream) {
    const float* x     = (const float*)d_in[0];
    const float* embed = (const float*)d_in[1];
    const float* sigma = (const float*)d_in[2];
    float* out = (float*)d_out;
    float* ws  = (float*)d_ws;

    float* embedT = ws;             // 512*64 = 32768 floats
    float* enorm  = ws + 32768;     // 512 floats
    float* lik    = ws + 33280;     // 512 floats

    prep_kernel<<<KCODES, DIMS, 0, stream>>>(embed, embedT, enorm, lik);
    main_kernel<<<NROWS / MTILE, NTHREADS, 0, stream>>>(x, embed, sigma,
                                                        embedT, enorm, lik, out);
    finish_kernel<<<1, NTHREADS, 0, stream>>>(lik, out);
}

// Round 7
// 562.393 us; speedup vs baseline: 1.1072x; 1.0437x over previous
//
#include <hip/hip_runtime.h>

#define NROWS    262144   // 16 * 16384
#define DIMS     64
#define KCODES   512
#define MTILE    32       // rows per block
#define RPW      4        // rows per wave (>=5 breaks the <=64-VGPR regime; R4: occ 68->24)
#define CHUNK    256      // epilogue col-half width (col->lane ownership, frozen)
#define NCHUNK   2        // col halves per lane (8 cols/lane total, frozen)
#define D_PER    16       // dims per LDS stage -> 16*512*4 = 32 KB
#define D_CHUNKS 4        // 64 / 16
#define NTHREADS 512

typedef float v2f __attribute__((ext_vector_type(2)));

// DPP lane-xor exchanges (VALU, not DS). quad_perm{1,0,3,2}=0xB1 is exactly
// lane^1; quad_perm{2,3,0,1}=0x4E is exactly lane^2 — same pairing as
// __shfl_xor, so reduction trees using them are bit-identical, but they run
// on the VALU instead of the shared-per-CU DS pipe.
__device__ __forceinline__ float dpp_xor1(float v) {
    int i = __builtin_amdgcn_update_dpp(0, __float_as_int(v), 0xB1, 0xF, 0xF, true);
    return __int_as_float(i);
}
__device__ __forceinline__ float dpp_xor2(float v) {
    int i = __builtin_amdgcn_update_dpp(0, __float_as_int(v), 0x4E, 0xF, 0xF, true);
    return __int_as_float(i);
}

// ---------------------------------------------------------------------------
// prep: embedT[k][d] = embed[d][k]; enorm[k] = sum_d embed[d][k]^2 (numpy
// pairwise-8 order); zero the likelihood accumulator.
// grid <<<512, 64>>> : block = one code k, lane = d.
// ---------------------------------------------------------------------------
__global__ void prep_kernel(const float* __restrict__ embed,
                            float* __restrict__ embedT,
                            float* __restrict__ enorm,
                            float* __restrict__ lik) {
    int k = blockIdx.x;
    int d = threadIdx.x;
    float v = embed[d * KCODES + k];
    embedT[k * DIMS + d] = v;
    float sq = __fmul_rn(v, v);
    // numpy pairwise: r_j = sq_j + sq_{j+8} + ... (sequential), j = d & 7
    int j = d & 7;
    float r = __shfl(sq, j, 64);
#pragma unroll
    for (int i = 1; i < 8; ++i)
        r = __fadd_rn(r, __shfl(sq, j + 8 * i, 64));
    // combine ((r0+r1)+(r2+r3)) + ((r4+r5)+(r6+r7)) via xor tree (bitwise exact)
    float t;
    t = __shfl_xor(r, 1, 64); r = __fadd_rn(r, t);
    t = __shfl_xor(r, 2, 64); r = __fadd_rn(r, t);
    t = __shfl_xor(r, 4, 64); r = __fadd_rn(r, t);
    if (d == 0) { enorm[k] = r; lik[k] = 0.0f; }
}

// ---------------------------------------------------------------------------
// main: fused GEMM + softmax + argmax + hard-gather + likelihood partials.
// grid <<<8192, 512>>>. Block: 32 rows x 512 cols. R3 structure (best 524us)
// with three bit-exact pipe-relief changes:
//
// (1) GEMM fma packed as v_pk_fma_f32 (float2 + __builtin_elementwise_fma):
//     2048 -> 1024 VALU instrs/thread. Per-component IEEE fma, per-acc chain
//     order unchanged -> bit-identical dots. z/exp phases stay scalar *_rn
//     (no vector ops there, so no contraction-rounding risk).
// (2) argmax without a shuffle tree: m is the exact row max, so the winning
//     cell has ee = expf(0.0f) = exactly 1.0f, and any cell that rounds to
//     1.0f is an ee-tie exactly as in the old (ov==bv && oc<bc) logic ->
//     argmax == min col with ee==1.0f: 2 ballots + 1 shfl vs 12 shuffles.
// (3) xor-1/xor-2 levels of the max/sum/xnorm trees via DPP quad_perm (VALU)
//     instead of DS shuffles — identical pairing, bit-identical sums.
// Rationale: R3 counters/pipe-model: GEMM DS ~164us, epilogue DS ~77us,
// VALU busy ~272us, nothing saturated -> shrink both VALU instr count and
// DS op count without touching the (frozen) GEMM DS traffic or numerics.
// R4/R5/R6 lessons: stay at RPW=4 / VGPR<=64 / R3 sync staging / unroll 2.
// ---------------------------------------------------------------------------
__launch_bounds__(NTHREADS)
__global__ void main_kernel(const float* __restrict__ x,
                            const float* __restrict__ embed,
                            const float* __restrict__ sigma,
                            const float* __restrict__ embedT,
                            const float* __restrict__ enorm,
                            float* __restrict__ lik,
                            float* __restrict__ out) {
    __shared__ float e_lds[D_PER * KCODES];   // 32 KB

    const int tid = threadIdx.x;
    const int cg  = tid & 63;        // col group (4 cols per half)
    const int rg  = tid >> 6;        // row group (4 rows), == wave id
    const int rowbase = blockIdx.x * MTILE + rg * RPW;

    const float sigma_v = sigma[0];

    // acc[c][r][p] = cols (cg*4 + 2p, cg*4 + 2p+1) of half c, row r
    v2f acc[NCHUNK][RPW][2];
#pragma unroll
    for (int c = 0; c < NCHUNK; ++c)
#pragma unroll
        for (int r = 0; r < RPW; ++r)
#pragma unroll
            for (int p = 0; p < 2; ++p) acc[c][r][p] = (v2f){0.0f, 0.0f};

    const float2* __restrict__ x2  = reinterpret_cast<const float2*>(x);
    const float4* __restrict__ eg4 = reinterpret_cast<const float4*>(embed);
    float4* e_lds4 = reinterpret_cast<float4*>(e_lds);

    for (int dc = 0; dc < D_CHUNKS; ++dc) {
        __syncthreads();   // protect previous stage's readers
        // stage e[dc*16 .. dc*16+15][0..511]: perfectly linear float4 copy
#pragma unroll
        for (int i = 0; i < 4; ++i) {
            int f4 = tid + i * NTHREADS;          // 0..2047
            e_lds4[f4] = eg4[dc * (D_PER * KCODES / 4) + f4];
        }
        __syncthreads();

        const float4* e4 = reinterpret_cast<const float4*>(e_lds);
        const int dbase = dc * (D_PER / 2);       // global dim-pair base
#pragma unroll 2
        for (int d2 = 0; d2 < D_PER / 2; ++d2) {  // dim pairs within stage
            float4 e0a = e4[(2 * d2 + 0) * 128 +  0 + cg];   // dim lo, half 0
            float4 e1a = e4[(2 * d2 + 1) * 128 +  0 + cg];   // dim hi, half 0
            float4 e0b = e4[(2 * d2 + 0) * 128 + 64 + cg];   // dim lo, half 1
            float4 e1b = e4[(2 * d2 + 1) * 128 + 64 + cg];   // dim hi, half 1
            v2f e0al = {e0a.x, e0a.y}, e0ah = {e0a.z, e0a.w};
            v2f e1al = {e1a.x, e1a.y}, e1ah = {e1a.z, e1a.w};
            v2f e0bl = {e0b.x, e0b.y}, e0bh = {e0b.z, e0b.w};
            v2f e1bl = {e1b.x, e1b.y}, e1bh = {e1b.z, e1b.w};
            int d2g = dbase + d2;                            // global dim-pair
#pragma unroll
            for (int r = 0; r < RPW; ++r) {
                float2 xv = x2[(size_t)(rowbase + r) * 32 + d2g];
                v2f xx = {xv.x, xv.x};
                v2f xy = {xv.y, xv.y};
                // ascending-d chain per accumulator (x.x then x.y) — bit-exact
                acc[0][r][0] = __builtin_elementwise_fma(xx, e0al, acc[0][r][0]);
                acc[0][r][1] = __builtin_elementwise_fma(xx, e0ah, acc[0][r][1]);
                acc[0][r][0] = __builtin_elementwise_fma(xy, e1al, acc[0][r][0]);
                acc[0][r][1] = __builtin_elementwise_fma(xy, e1ah, acc[0][r][1]);
                acc[1][r][0] = __builtin_elementwise_fma(xx, e0bl, acc[1][r][0]);
                acc[1][r][1] = __builtin_elementwise_fma(xx, e0bh, acc[1][r][1]);
                acc[1][r][0] = __builtin_elementwise_fma(xy, e1bl, acc[1][r][0]);
                acc[1][r][1] = __builtin_elementwise_fma(xy, e1bh, acc[1][r][1]);
            }
        }
    }

    // ---- xnorm for the wave's 4 rows, numpy pairwise-8 order ----
    // lane cg = r_l*8 + j_l computes partial r_{j_l} of row (r_l & 3); the
    // upper 32 lanes duplicate rows 0-3 (keeps the 8-lane xor tree bit-exact
    // and avoids reading rows outside this wave's ownership).
    const int r_l = (cg >> 3) & 3;
    const int j_l = cg & 7;
    float xr;
    {
        const float* xp = x + (size_t)(rowbase + r_l) * DIMS + j_l;
        float v0 = xp[0];
        float s = __fmul_rn(v0, v0);
#pragma unroll
        for (int i = 1; i < 8; ++i) {
            float v = xp[8 * i];
            s = __fadd_rn(s, __fmul_rn(v, v));
        }
        xr = s;
    }
    {
        float t;
        t = dpp_xor1(xr);          xr = __fadd_rn(xr, t);
        t = dpp_xor2(xr);          xr = __fadd_rn(xr, t);
        t = __shfl_xor(xr, 4, 64); xr = __fadd_rn(xr, t);
    }
    // lane r*8+j now holds xnorm of row r (r = 0..3)

    // enorm for this thread's 8 cols (scalar loads, identical to before)
    float en[NCHUNK][4];
#pragma unroll
    for (int c = 0; c < NCHUNK; ++c)
#pragma unroll
        for (int q = 0; q < 4; ++q)
            en[c][q] = enorm[c * CHUNK + cg * 4 + q];

    float likpart[NCHUNK][4];
#pragma unroll
    for (int c = 0; c < NCHUNK; ++c)
#pragma unroll
        for (int q = 0; q < 4; ++q) likpart[c][q] = 0.0f;

#define ACC(c, r, q) (acc[c][r][(q) >> 1][(q) & 1])

#pragma unroll
    for (int r = 0; r < RPW; ++r) {
        float xn = __shfl(xr, r * 8, 64);
        // z = -sigma * ((xnorm - 2*dot) + enorm), np-assembly order, scalar
        // *_rn ops (no contraction). IN-PLACE over acc components.
        float m = -INFINITY;
#pragma unroll
        for (int c = 0; c < NCHUNK; ++c)
#pragma unroll
            for (int q = 0; q < 4; ++q) {
                float dot  = ACC(c, r, q);
                float td   = __fsub_rn(xn, __fmul_rn(2.0f, dot));
                float dist = __fadd_rn(td, en[c][q]);
                float zz   = __fmul_rn(-sigma_v, dist);
                ACC(c, r, q) = zz;
                m = fmaxf(m, zz);
            }
        m = fmaxf(m, dpp_xor1(m));
        m = fmaxf(m, dpp_xor2(m));
        m = fmaxf(m, __shfl_xor(m,  4, 64));
        m = fmaxf(m, __shfl_xor(m,  8, 64));
        m = fmaxf(m, __shfl_xor(m, 16, 64));
        m = fmaxf(m, __shfl_xor(m, 32, 64));

        // ev overwrites z in place; track local min col with ee == 1.0f
        // (the global max ee is exactly expf(0)=1.0f; cells rounding to 1.0f
        // are ee-ties — identical semantics to the old (ov==bv && oc<bc)).
        float s = 0.0f;
        int lcol = 1024;
#pragma unroll
        for (int c = 0; c < NCHUNK; ++c)
#pragma unroll
            for (int q = 0; q < 4; ++q) {
                float ee = expf(__fsub_rn(ACC(c, r, q), m));
                ACC(c, r, q) = ee;
                s += ee;
                int col = c * CHUNK + cg * 4 + q;
                lcol = (ee == 1.0f) ? min(lcol, col) : lcol;
            }
        // first-index argmax via ballots: lowest cg holding a half-0
        // candidate wins (cols ascend with cg), else lowest cg with any.
        unsigned long long b0 = __ballot(lcol < CHUNK);
        unsigned long long ba = __ballot(lcol < 1024);
        int srcl = (int)(b0 ? __ffsll(b0) : __ffsll(ba)) - 1;
        int bc = __shfl(lcol, srcl, 64);

        s = __fadd_rn(s, dpp_xor1(s));
        s = __fadd_rn(s, dpp_xor2(s));
        s = __fadd_rn(s, __shfl_xor(s,  4, 64));
        s = __fadd_rn(s, __shfl_xor(s,  8, 64));
        s = __fadd_rn(s, __shfl_xor(s, 16, 64));
        s = __fadd_rn(s, __shfl_xor(s, 32, 64));

        float invS = 1.0f / s;
#pragma unroll
        for (int c = 0; c < NCHUNK; ++c)
#pragma unroll
            for (int q = 0; q < 4; ++q)
                likpart[c][q] = fmaf(ACC(c, r, q), invS, likpart[c][q]);

        // hard-gather write: quantize[row][cg] = embedT[bc][cg]
        // nontemporal: avoid write-allocate RFO on the 64 MB output
        int row = rowbase + r;
        __builtin_nontemporal_store(embedT[bc * DIMS + cg],
                                    &out[(size_t)row * DIMS + cg]);
    }
#undef ACC

    // ---- block-level likelihood reduction (reuse e_lds) ----
    float* red = e_lds;
    __syncthreads();
    red[tid] = 0.0f;
    __syncthreads();
#pragma unroll
    for (int c = 0; c < NCHUNK; ++c)
#pragma unroll
        for (int q = 0; q < 4; ++q)
            atomicAdd(&red[c * CHUNK + cg * 4 + q], likpart[c][q]);
    __syncthreads();
    atomicAdd(&lik[tid], red[tid]);
}

// ---------------------------------------------------------------------------
// finish: likelihoods = lik_sum / N; quant_loss = 0.25 * mean(p*(log p - log(l+eps)))
// ---------------------------------------------------------------------------
__global__ void finish_kernel(const float* __restrict__ lik,
                              float* __restrict__ out) {
    int tid = threadIdx.x;   // 512 threads
    float l = lik[tid] / 262144.0f;     // exact: divide by 2^18
    out[16777217 + tid] = l;
    const float p = 1.0f / 512.0f;
    float term = __fmul_rn(p, __fsub_rn(logf(p), logf(l + 1e-10f)));
#pragma unroll
    for (int mask = 1; mask < 64; mask <<= 1)
        term += __shfl_xor(term, mask, 64);
    __shared__ float ws[8];
    if ((tid & 63) == 0) ws[tid >> 6] = term;
    __syncthreads();
    if (tid == 0) {
        float ssum = 0.0f;
        for (int i = 0; i < 8; ++i) ssum += ws[i];
        out[16777216] = 0.25f * (ssum / 512.0f);
    }
}

extern "C" void kernel_launch(void* const* d_in, const int* in_sizes, int n_in,
                              void* d_out, int out_size, void* d_ws, size_t ws_size,
                              hipStream_t stream) {
    const float* x     = (const float*)d_in[0];
    const float* embed = (const float*)d_in[1];
    const float* sigma = (const float*)d_in[2];
    float* out = (float*)d_out;
    float* ws  = (float*)d_ws;

    float* embedT = ws;             // 512*64 = 32768 floats
    float* enorm  = ws + 32768;     // 512 floats
    float* lik    = ws + 33280;     // 512 floats

    prep_kernel<<<KCODES, DIMS, 0, stream>>>(embed, embedT, enorm, lik);
    main_kernel<<<NROWS / MTILE, NTHREADS, 0, stream>>>(x, embed, sigma,
                                                        embedT, enorm, lik, out);
    finish_kernel<<<1, NTHREADS, 0, stream>>>(lik, out);
}

// Round 8
// 543.388 us; speedup vs baseline: 1.1459x; 1.0350x over previous
//
#include <hip/hip_runtime.h>

#define NROWS    262144   // 16 * 16384
#define DIMS     64
#define KCODES   512
#define MTILE    32       // rows per block
#define RPW      4        // rows per wave (>=5 breaks the <=64-VGPR regime; R4: occ 68->24)
#define CHUNK    256      // epilogue col-half width (col->lane ownership, frozen)
#define NCHUNK   2        // col halves per lane (8 cols/lane total, frozen)
#define D_PER    16       // dims per LDS stage -> 16*512*4 = 32 KB
#define D_CHUNKS 4        // 64 / 16
#define NTHREADS 512

typedef float v2f __attribute__((ext_vector_type(2)));

// Packed fp32 FMA with dword-broadcast of src0 via op_sel (CDNA VOP3P).
// v_pk_fma_f32 sources are 64-bit f32 pairs; op_sel[0]/op_sel_hi[0] pick
// which dword of src0 feeds the low/high lane result. Per-component it is
// the same IEEE fma as fmaf -> chains stay bit-exact.
//   lo-broadcast: both results use xv.x  -> op_sel:[0,0,0] op_sel_hi:[0,1,1]
//   hi-broadcast: both results use xv.y  -> op_sel:[1,0,0] op_sel_hi:[1,1,1]
// R7 lesson: __builtin_elementwise_fma did NOT emit v_pk_fma_f32 (VALU busy
// stayed ~254us vs ~150 predicted) — force it.
__device__ __forceinline__ void pk_fma_lo(v2f& a, v2f xv, v2f e) {
    asm("v_pk_fma_f32 %0, %1, %2, %0 op_sel:[0,0,0] op_sel_hi:[0,1,1]"
        : "+v"(a) : "v"(xv), "v"(e));
}
__device__ __forceinline__ void pk_fma_hi(v2f& a, v2f xv, v2f e) {
    asm("v_pk_fma_f32 %0, %1, %2, %0 op_sel:[1,0,0] op_sel_hi:[1,1,1]"
        : "+v"(a) : "v"(xv), "v"(e));
}

// DPP lane-xor exchanges (VALU, not DS). quad_perm{1,0,3,2}=0xB1 is exactly
// lane^1; quad_perm{2,3,0,1}=0x4E is exactly lane^2 — same pairing as
// __shfl_xor, so reduction trees using them are bit-identical, but they run
// on the VALU instead of the shared-per-CU DS pipe.
__device__ __forceinline__ float dpp_xor1(float v) {
    int i = __builtin_amdgcn_update_dpp(0, __float_as_int(v), 0xB1, 0xF, 0xF, true);
    return __int_as_float(i);
}
__device__ __forceinline__ float dpp_xor2(float v) {
    int i = __builtin_amdgcn_update_dpp(0, __float_as_int(v), 0x4E, 0xF, 0xF, true);
    return __int_as_float(i);
}

// ---------------------------------------------------------------------------
// prep: embedT[k][d] = embed[d][k]; enorm[k] = sum_d embed[d][k]^2 (numpy
// pairwise-8 order); zero the likelihood accumulator.
// grid <<<512, 64>>> : block = one code k, lane = d.
// ---------------------------------------------------------------------------
__global__ void prep_kernel(const float* __restrict__ embed,
                            float* __restrict__ embedT,
                            float* __restrict__ enorm,
                            float* __restrict__ lik) {
    int k = blockIdx.x;
    int d = threadIdx.x;
    float v = embed[d * KCODES + k];
    embedT[k * DIMS + d] = v;
    float sq = __fmul_rn(v, v);
    // numpy pairwise: r_j = sq_j + sq_{j+8} + ... (sequential), j = d & 7
    int j = d & 7;
    float r = __shfl(sq, j, 64);
#pragma unroll
    for (int i = 1; i < 8; ++i)
        r = __fadd_rn(r, __shfl(sq, j + 8 * i, 64));
    // combine ((r0+r1)+(r2+r3)) + ((r4+r5)+(r6+r7)) via xor tree (bitwise exact)
    float t;
    t = __shfl_xor(r, 1, 64); r = __fadd_rn(r, t);
    t = __shfl_xor(r, 2, 64); r = __fadd_rn(r, t);
    t = __shfl_xor(r, 4, 64); r = __fadd_rn(r, t);
    if (d == 0) { enorm[k] = r; lik[k] = 0.0f; }
}

// ---------------------------------------------------------------------------
// main: fused GEMM + softmax + argmax + hard-gather + likelihood partials.
// grid <<<8192, 512>>>. Block: 32 rows x 512 cols. R7 structure (best 504us)
// with the GEMM inner loop forced to v_pk_fma_f32 via inline asm + op_sel
// dword broadcast (no movs). Per (r,d2): 8 packed fma replace 16 scalar.
// Chain order per accumulator unchanged (x.x*e_lo then x.y*e_hi, ascending
// d) -> bit-identical dots. Epilogue (DPP trees, ballot argmax, ee==1.0f)
// and sync staging kept from R7. R4/R5/R6 lessons: RPW=4, VGPR<=64,
// unroll 2, no async staging.
// ---------------------------------------------------------------------------
__launch_bounds__(NTHREADS)
__global__ void main_kernel(const float* __restrict__ x,
                            const float* __restrict__ embed,
                            const float* __restrict__ sigma,
                            const float* __restrict__ embedT,
                            const float* __restrict__ enorm,
                            float* __restrict__ lik,
                            float* __restrict__ out) {
    __shared__ float e_lds[D_PER * KCODES];   // 32 KB

    const int tid = threadIdx.x;
    const int cg  = tid & 63;        // col group (4 cols per half)
    const int rg  = tid >> 6;        // row group (4 rows), == wave id
    const int rowbase = blockIdx.x * MTILE + rg * RPW;

    const float sigma_v = sigma[0];

    // acc[c][r][p] = cols (cg*4 + 2p, cg*4 + 2p+1) of half c, row r
    v2f acc[NCHUNK][RPW][2];
#pragma unroll
    for (int c = 0; c < NCHUNK; ++c)
#pragma unroll
        for (int r = 0; r < RPW; ++r)
#pragma unroll
            for (int p = 0; p < 2; ++p) acc[c][r][p] = (v2f){0.0f, 0.0f};

    const float2* __restrict__ x2  = reinterpret_cast<const float2*>(x);
    const float4* __restrict__ eg4 = reinterpret_cast<const float4*>(embed);
    float4* e_lds4 = reinterpret_cast<float4*>(e_lds);

    for (int dc = 0; dc < D_CHUNKS; ++dc) {
        __syncthreads();   // protect previous stage's readers
        // stage e[dc*16 .. dc*16+15][0..511]: perfectly linear float4 copy
#pragma unroll
        for (int i = 0; i < 4; ++i) {
            int f4 = tid + i * NTHREADS;          // 0..2047
            e_lds4[f4] = eg4[dc * (D_PER * KCODES / 4) + f4];
        }
        __syncthreads();

        const float4* e4 = reinterpret_cast<const float4*>(e_lds);
        const int dbase = dc * (D_PER / 2);       // global dim-pair base
#pragma unroll 2
        for (int d2 = 0; d2 < D_PER / 2; ++d2) {  // dim pairs within stage
            float4 e0a = e4[(2 * d2 + 0) * 128 +  0 + cg];   // dim lo, half 0
            float4 e1a = e4[(2 * d2 + 1) * 128 +  0 + cg];   // dim hi, half 0
            float4 e0b = e4[(2 * d2 + 0) * 128 + 64 + cg];   // dim lo, half 1
            float4 e1b = e4[(2 * d2 + 1) * 128 + 64 + cg];   // dim hi, half 1
            v2f e0al = {e0a.x, e0a.y}, e0ah = {e0a.z, e0a.w};
            v2f e1al = {e1a.x, e1a.y}, e1ah = {e1a.z, e1a.w};
            v2f e0bl = {e0b.x, e0b.y}, e0bh = {e0b.z, e0b.w};
            v2f e1bl = {e1b.x, e1b.y}, e1bh = {e1b.z, e1b.w};
            int d2g = dbase + d2;                            // global dim-pair
#pragma unroll
            for (int r = 0; r < RPW; ++r) {
                float2 xv = x2[(size_t)(rowbase + r) * 32 + d2g];
                v2f xvp = {xv.x, xv.y};
                // per accumulator: fma(x.x, e_dimlo) then fma(x.y, e_dimhi)
                // — identical chain to the scalar version, bit-exact.
                pk_fma_lo(acc[0][r][0], xvp, e0al);
                pk_fma_lo(acc[0][r][1], xvp, e0ah);
                pk_fma_hi(acc[0][r][0], xvp, e1al);
                pk_fma_hi(acc[0][r][1], xvp, e1ah);
                pk_fma_lo(acc[1][r][0], xvp, e0bl);
                pk_fma_lo(acc[1][r][1], xvp, e0bh);
                pk_fma_hi(acc[1][r][0], xvp, e1bl);
                pk_fma_hi(acc[1][r][1], xvp, e1bh);
            }
        }
    }

    // ---- xnorm for the wave's 4 rows, numpy pairwise-8 order ----
    // lane cg = r_l*8 + j_l computes partial r_{j_l} of row (r_l & 3); the
    // upper 32 lanes duplicate rows 0-3 (keeps the 8-lane xor tree bit-exact
    // and avoids reading rows outside this wave's ownership).
    const int r_l = (cg >> 3) & 3;
    const int j_l = cg & 7;
    float xr;
    {
        const float* xp = x + (size_t)(rowbase + r_l) * DIMS + j_l;
        float v0 = xp[0];
        float s = __fmul_rn(v0, v0);
#pragma unroll
        for (int i = 1; i < 8; ++i) {
            float v = xp[8 * i];
            s = __fadd_rn(s, __fmul_rn(v, v));
        }
        xr = s;
    }
    {
        float t;
        t = dpp_xor1(xr);          xr = __fadd_rn(xr, t);
        t = dpp_xor2(xr);          xr = __fadd_rn(xr, t);
        t = __shfl_xor(xr, 4, 64); xr = __fadd_rn(xr, t);
    }
    // lane r*8+j now holds xnorm of row r (r = 0..3)

    // enorm for this thread's 8 cols (scalar loads, identical to before)
    float en[NCHUNK][4];
#pragma unroll
    for (int c = 0; c < NCHUNK; ++c)
#pragma unroll
        for (int q = 0; q < 4; ++q)
            en[c][q] = enorm[c * CHUNK + cg * 4 + q];

    float likpart[NCHUNK][4];
#pragma unroll
    for (int c = 0; c < NCHUNK; ++c)
#pragma unroll
        for (int q = 0; q < 4; ++q) likpart[c][q] = 0.0f;

#define ACC(c, r, q) (acc[c][r][(q) >> 1][(q) & 1])

#pragma unroll
    for (int r = 0; r < RPW; ++r) {
        float xn = __shfl(xr, r * 8, 64);
        // z = -sigma * ((xnorm - 2*dot) + enorm), np-assembly order, scalar
        // *_rn ops (no contraction). IN-PLACE over acc components.
        float m = -INFINITY;
#pragma unroll
        for (int c = 0; c < NCHUNK; ++c)
#pragma unroll
            for (int q = 0; q < 4; ++q) {
                float dot  = ACC(c, r, q);
                float td   = __fsub_rn(xn, __fmul_rn(2.0f, dot));
                float dist = __fadd_rn(td, en[c][q]);
                float zz   = __fmul_rn(-sigma_v, dist);
                ACC(c, r, q) = zz;
                m = fmaxf(m, zz);
            }
        m = fmaxf(m, dpp_xor1(m));
        m = fmaxf(m, dpp_xor2(m));
        m = fmaxf(m, __shfl_xor(m,  4, 64));
        m = fmaxf(m, __shfl_xor(m,  8, 64));
        m = fmaxf(m, __shfl_xor(m, 16, 64));
        m = fmaxf(m, __shfl_xor(m, 32, 64));

        // ev overwrites z in place; track local min col with ee == 1.0f
        // (the global max ee is exactly expf(0)=1.0f; cells rounding to 1.0f
        // are ee-ties — identical semantics to the old (ov==bv && oc<bc)).
        float s = 0.0f;
        int lcol = 1024;
#pragma unroll
        for (int c = 0; c < NCHUNK; ++c)
#pragma unroll
            for (int q = 0; q < 4; ++q) {
                float ee = expf(__fsub_rn(ACC(c, r, q), m));
                ACC(c, r, q) = ee;
                s += ee;
                int col = c * CHUNK + cg * 4 + q;
                lcol = (ee == 1.0f) ? min(lcol, col) : lcol;
            }
        // first-index argmax via ballots: lowest cg holding a half-0
        // candidate wins (cols ascend with cg), else lowest cg with any.
        unsigned long long b0 = __ballot(lcol < CHUNK);
        unsigned long long ba = __ballot(lcol < 1024);
        int srcl = (int)(b0 ? __ffsll(b0) : __ffsll(ba)) - 1;
        int bc = __shfl(lcol, srcl, 64);

        s = __fadd_rn(s, dpp_xor1(s));
        s = __fadd_rn(s, dpp_xor2(s));
        s = __fadd_rn(s, __shfl_xor(s,  4, 64));
        s = __fadd_rn(s, __shfl_xor(s,  8, 64));
        s = __fadd_rn(s, __shfl_xor(s, 16, 64));
        s = __fadd_rn(s, __shfl_xor(s, 32, 64));

        float invS = 1.0f / s;
#pragma unroll
        for (int c = 0; c < NCHUNK; ++c)
#pragma unroll
            for (int q = 0; q < 4; ++q)
                likpart[c][q] = fmaf(ACC(c, r, q), invS, likpart[c][q]);

        // hard-gather write: quantize[row][cg] = embedT[bc][cg]
        // nontemporal: avoid write-allocate RFO on the 64 MB output
        int row = rowbase + r;
        __builtin_nontemporal_store(embedT[bc * DIMS + cg],
                                    &out[(size_t)row * DIMS + cg]);
    }
#undef ACC

    // ---- block-level likelihood reduction (reuse e_lds) ----
    float* red = e_lds;
    __syncthreads();
    red[tid] = 0.0f;
    __syncthreads();
#pragma unroll
    for (int c = 0; c < NCHUNK; ++c)
#pragma unroll
        for (int q = 0; q < 4; ++q)
            atomicAdd(&red[c * CHUNK + cg * 4 + q], likpart[c][q]);
    __syncthreads();
    atomicAdd(&lik[tid], red[tid]);
}

// ---------------------------------------------------------------------------
// finish: likelihoods = lik_sum / N; quant_loss = 0.25 * mean(p*(log p - log(l+eps)))
// ---------------------------------------------------------------------------
__global__ void finish_kernel(const float* __restrict__ lik,
                              float* __restrict__ out) {
    int tid = threadIdx.x;   // 512 threads
    float l = lik[tid] / 262144.0f;     // exact: divide by 2^18
    out[16777217 + tid] = l;
    const float p = 1.0f / 512.0f;
    float term = __fmul_rn(p, __fsub_rn(logf(p), logf(l + 1e-10f)));
#pragma unroll
    for (int mask = 1; mask < 64; mask <<= 1)
        term += __shfl_xor(term, mask, 64);
    __shared__ float ws[8];
    if ((tid & 63) == 0) ws[tid >> 6] = term;
    __syncthreads();
    if (tid == 0) {
        float ssum = 0.0f;
        for (int i = 0; i < 8; ++i) ssum += ws[i];
        out[16777216] = 0.25f * (ssum / 512.0f);
    }
}

extern "C" void kernel_launch(void* const* d_in, const int* in_sizes, int n_in,
                              void* d_out, int out_size, void* d_ws, size_t ws_size,
                              hipStream_t stream) {
    const float* x     = (const float*)d_in[0];
    const float* embed = (const float*)d_in[1];
    const float* sigma = (const float*)d_in[2];
    float* out = (float*)d_out;
    float* ws  = (float*)d_ws;

    float* embedT = ws;             // 512*64 = 32768 floats
    float* enorm  = ws + 32768;     // 512 floats
    float* lik    = ws + 33280;     // 512 floats

    prep_kernel<<<KCODES, DIMS, 0, stream>>>(embed, embedT, enorm, lik);
    main_kernel<<<NROWS / MTILE, NTHREADS, 0, stream>>>(x, embed, sigma,
                                                        embedT, enorm, lik, out);
    finish_kernel<<<1, NTHREADS, 0, stream>>>(lik, out);
}

// Round 9
// 506.278 us; speedup vs baseline: 1.2299x; 1.0733x over previous
//
#include <hip/hip_runtime.h>

#define NROWS    262144   // 16 * 16384
#define DIMS     64
#define KCODES   512
#define MTILE    32       // rows per block
#define RPW      4        // rows per wave (>=5 breaks the <=64-VGPR regime; R4: occ 68->24)
#define CHUNK    256      // epilogue col-half width (col->lane ownership, frozen)
#define NCHUNK   2        // col halves per lane (8 cols/lane total, frozen)
#define D_PER    16       // dims per LDS stage -> 16*512*4 = 32 KB
#define D_CHUNKS 4        // 64 / 16
#define NTHREADS 512

typedef int v8i __attribute__((ext_vector_type(8)));

// DPP lane-xor exchanges (VALU, not DS). quad_perm{1,0,3,2}=0xB1 is exactly
// lane^1; quad_perm{2,3,0,1}=0x4E is exactly lane^2 — same pairing as
// __shfl_xor, so reduction trees using them are bit-identical, but they run
// on the VALU instead of the shared-per-CU DS pipe.
__device__ __forceinline__ float dpp_xor1(float v) {
    int i = __builtin_amdgcn_update_dpp(0, __float_as_int(v), 0xB1, 0xF, 0xF, true);
    return __int_as_float(i);
}
__device__ __forceinline__ float dpp_xor2(float v) {
    int i = __builtin_amdgcn_update_dpp(0, __float_as_int(v), 0x4E, 0xF, 0xF, true);
    return __int_as_float(i);
}

// ---------------------------------------------------------------------------
// prep: embedT[k][d] = embed[d][k]; enorm[k] = sum_d embed[d][k]^2 (numpy
// pairwise-8 order); zero the likelihood accumulator.
// grid <<<512, 64>>> : block = one code k, lane = d.
// ---------------------------------------------------------------------------
__global__ void prep_kernel(const float* __restrict__ embed,
                            float* __restrict__ embedT,
                            float* __restrict__ enorm,
                            float* __restrict__ lik) {
    int k = blockIdx.x;
    int d = threadIdx.x;
    float v = embed[d * KCODES + k];
    embedT[k * DIMS + d] = v;
    float sq = __fmul_rn(v, v);
    // numpy pairwise: r_j = sq_j + sq_{j+8} + ... (sequential), j = d & 7
    int j = d & 7;
    float r = __shfl(sq, j, 64);
#pragma unroll
    for (int i = 1; i < 8; ++i)
        r = __fadd_rn(r, __shfl(sq, j + 8 * i, 64));
    // combine ((r0+r1)+(r2+r3)) + ((r4+r5)+(r6+r7)) via xor tree (bitwise exact)
    float t;
    t = __shfl_xor(r, 1, 64); r = __fadd_rn(r, t);
    t = __shfl_xor(r, 2, 64); r = __fadd_rn(r, t);
    t = __shfl_xor(r, 4, 64); r = __fadd_rn(r, t);
    if (d == 0) { enorm[k] = r; lik[k] = 0.0f; }
}

// ---------------------------------------------------------------------------
// main: fused GEMM + softmax + argmax + hard-gather + likelihood partials.
// grid <<<8192, 512>>>. Block: 32 rows x 512 cols. R7/R8 structure with one
// change:
//
// ROUND-9: x rows into SGPRs via s_load_dwordx8. Within a wave the x value
// for row r is identical across all 64 lanes (lanes differ only in columns)
// — the per-(r,d2) global_load_dwordx2 was a broadcast load, 128 VMEM
// ops/thread sitting on the fma dependency chain (R8 showed packed fma
// issues at half rate -> VALU pipe time is a 109us floor; the remaining
// ~250us is stalls, dominated by these loads). Now: per stage & phase, 4
// s_load_dwordx8 (one per row, 32B) + s_waitcnt inside ONE asm block whose
// outputs the fmas data-depend on (no hoisting hazard); fma becomes
// v_fmac_f32 v,s,v (SGPR src0 legal, scalar pipe feeds it for free). Zero
// VMEM in the GEMM loop. fma chains are the R3 scalar form, ascending d per
// accumulator -> bit-identical. Epilogue (DPP trees, ballot argmax,
// ee==1.0f) unchanged from R8. RPW=4 / VGPR<=64 / sync staging / unroll-2
// lessons kept (R4/R5/R6).
// ---------------------------------------------------------------------------
__launch_bounds__(NTHREADS)
__global__ void main_kernel(const float* __restrict__ x,
                            const float* __restrict__ embed,
                            const float* __restrict__ sigma,
                            const float* __restrict__ embedT,
                            const float* __restrict__ enorm,
                            float* __restrict__ lik,
                            float* __restrict__ out) {
    __shared__ float e_lds[D_PER * KCODES];   // 32 KB

    const int tid = threadIdx.x;
    const int cg  = tid & 63;        // col group (4 cols per half)
    const int rg  = tid >> 6;        // row group (4 rows), == wave id
    const int rowbase = blockIdx.x * MTILE + rg * RPW;

    const float sigma_v = sigma[0];

    float acc[NCHUNK][RPW][4];
#pragma unroll
    for (int c = 0; c < NCHUNK; ++c)
#pragma unroll
        for (int r = 0; r < RPW; ++r)
#pragma unroll
            for (int q = 0; q < 4; ++q) acc[c][r][q] = 0.0f;

    const float4* __restrict__ eg4 = reinterpret_cast<const float4*>(embed);
    float4* e_lds4 = reinterpret_cast<float4*>(e_lds);

    // wave-uniform x base (SGPR): all lanes of this wave share these 4 rows
    const int rg_s = __builtin_amdgcn_readfirstlane(rg);
    const float* xwave = x + (size_t)(blockIdx.x * MTILE + rg_s * RPW) * DIMS;

    for (int dc = 0; dc < D_CHUNKS; ++dc) {
        __syncthreads();   // protect previous stage's readers
        // stage e[dc*16 .. dc*16+15][0..511]: perfectly linear float4 copy
#pragma unroll
        for (int i = 0; i < 4; ++i) {
            int f4 = tid + i * NTHREADS;          // 0..2047
            e_lds4[f4] = eg4[dc * (D_PER * KCODES / 4) + f4];
        }
        __syncthreads();

        const float4* e4 = reinterpret_cast<const float4*>(e_lds);

#pragma unroll
        for (int ph = 0; ph < 2; ++ph) {
            // 4 rows x 8 dims (32 B/row) into SGPRs; wait folded into the
            // asm so every consumer data-depends on completed loads.
            const float* p0 = xwave + 0 * DIMS + dc * D_PER + ph * 8;
            const float* p1 = xwave + 1 * DIMS + dc * D_PER + ph * 8;
            const float* p2 = xwave + 2 * DIMS + dc * D_PER + ph * 8;
            const float* p3 = xwave + 3 * DIMS + dc * D_PER + ph * 8;
            v8i xs0, xs1, xs2, xs3;
            asm volatile("s_load_dwordx8 %0, %4, 0\n\t"
                         "s_load_dwordx8 %1, %5, 0\n\t"
                         "s_load_dwordx8 %2, %6, 0\n\t"
                         "s_load_dwordx8 %3, %7, 0\n\t"
                         "s_waitcnt lgkmcnt(0)"
                         : "=&s"(xs0), "=&s"(xs1), "=&s"(xs2), "=&s"(xs3)
                         : "s"(p0), "s"(p1), "s"(p2), "s"(p3));

#pragma unroll
            for (int d2l = 0; d2l < 4; ++d2l) {   // dim pairs within phase
                const int d2 = ph * 4 + d2l;
                float4 e0a = e4[(2 * d2 + 0) * 128 +  0 + cg];  // dim lo, h0
                float4 e1a = e4[(2 * d2 + 1) * 128 +  0 + cg];  // dim hi, h0
                float4 e0b = e4[(2 * d2 + 0) * 128 + 64 + cg];  // dim lo, h1
                float4 e1b = e4[(2 * d2 + 1) * 128 + 64 + cg];  // dim hi, h1

#define ROW_FMA(r, xs)                                                        \
                {                                                             \
                    float xlo = __int_as_float(xs[2 * d2l]);                  \
                    float xhi = __int_as_float(xs[2 * d2l + 1]);              \
                    acc[0][r][0] = fmaf(xlo, e0a.x, acc[0][r][0]);            \
                    acc[0][r][1] = fmaf(xlo, e0a.y, acc[0][r][1]);            \
                    acc[0][r][2] = fmaf(xlo, e0a.z, acc[0][r][2]);            \
                    acc[0][r][3] = fmaf(xlo, e0a.w, acc[0][r][3]);            \
                    acc[0][r][0] = fmaf(xhi, e1a.x, acc[0][r][0]);            \
                    acc[0][r][1] = fmaf(xhi, e1a.y, acc[0][r][1]);            \
                    acc[0][r][2] = fmaf(xhi, e1a.z, acc[0][r][2]);            \
                    acc[0][r][3] = fmaf(xhi, e1a.w, acc[0][r][3]);            \
                    acc[1][r][0] = fmaf(xlo, e0b.x, acc[1][r][0]);            \
                    acc[1][r][1] = fmaf(xlo, e0b.y, acc[1][r][1]);            \
                    acc[1][r][2] = fmaf(xlo, e0b.z, acc[1][r][2]);            \
                    acc[1][r][3] = fmaf(xlo, e0b.w, acc[1][r][3]);            \
                    acc[1][r][0] = fmaf(xhi, e1b.x, acc[1][r][0]);            \
                    acc[1][r][1] = fmaf(xhi, e1b.y, acc[1][r][1]);            \
                    acc[1][r][2] = fmaf(xhi, e1b.z, acc[1][r][2]);            \
                    acc[1][r][3] = fmaf(xhi, e1b.w, acc[1][r][3]);            \
                }
                ROW_FMA(0, xs0)
                ROW_FMA(1, xs1)
                ROW_FMA(2, xs2)
                ROW_FMA(3, xs3)
#undef ROW_FMA
            }
        }
    }

    // ---- xnorm for the wave's 4 rows, numpy pairwise-8 order ----
    // lane cg = r_l*8 + j_l computes partial r_{j_l} of row (r_l & 3); the
    // upper 32 lanes duplicate rows 0-3 (keeps the 8-lane xor tree bit-exact
    // and avoids reading rows outside this wave's ownership).
    const int r_l = (cg >> 3) & 3;
    const int j_l = cg & 7;
    float xr;
    {
        const float* xp = x + (size_t)(rowbase + r_l) * DIMS + j_l;
        float v0 = xp[0];
        float s = __fmul_rn(v0, v0);
#pragma unroll
        for (int i = 1; i < 8; ++i) {
            float v = xp[8 * i];
            s = __fadd_rn(s, __fmul_rn(v, v));
        }
        xr = s;
    }
    {
        float t;
        t = dpp_xor1(xr);          xr = __fadd_rn(xr, t);
        t = dpp_xor2(xr);          xr = __fadd_rn(xr, t);
        t = __shfl_xor(xr, 4, 64); xr = __fadd_rn(xr, t);
    }
    // lane r*8+j now holds xnorm of row r (r = 0..3)

    // enorm for this thread's 8 cols (scalar loads, identical to before)
    float en[NCHUNK][4];
#pragma unroll
    for (int c = 0; c < NCHUNK; ++c)
#pragma unroll
        for (int q = 0; q < 4; ++q)
            en[c][q] = enorm[c * CHUNK + cg * 4 + q];

    float likpart[NCHUNK][4];
#pragma unroll
    for (int c = 0; c < NCHUNK; ++c)
#pragma unroll
        for (int q = 0; q < 4; ++q) likpart[c][q] = 0.0f;

#pragma unroll
    for (int r = 0; r < RPW; ++r) {
        float xn = __shfl(xr, r * 8, 64);
        // z = -sigma * ((xnorm - 2*dot) + enorm), np-assembly order, scalar
        // *_rn ops (no contraction). IN-PLACE over acc.
        float m = -INFINITY;
#pragma unroll
        for (int c = 0; c < NCHUNK; ++c)
#pragma unroll
            for (int q = 0; q < 4; ++q) {
                float dot  = acc[c][r][q];
                float td   = __fsub_rn(xn, __fmul_rn(2.0f, dot));
                float dist = __fadd_rn(td, en[c][q]);
                float zz   = __fmul_rn(-sigma_v, dist);
                acc[c][r][q] = zz;
                m = fmaxf(m, zz);
            }
        m = fmaxf(m, dpp_xor1(m));
        m = fmaxf(m, dpp_xor2(m));
        m = fmaxf(m, __shfl_xor(m,  4, 64));
        m = fmaxf(m, __shfl_xor(m,  8, 64));
        m = fmaxf(m, __shfl_xor(m, 16, 64));
        m = fmaxf(m, __shfl_xor(m, 32, 64));

        // ev overwrites z in place; track local min col with ee == 1.0f
        // (the global max ee is exactly expf(0)=1.0f; cells rounding to 1.0f
        // are ee-ties — identical semantics to the old (ov==bv && oc<bc)).
        float s = 0.0f;
        int lcol = 1024;
#pragma unroll
        for (int c = 0; c < NCHUNK; ++c)
#pragma unroll
            for (int q = 0; q < 4; ++q) {
                float ee = expf(__fsub_rn(acc[c][r][q], m));
                acc[c][r][q] = ee;
                s += ee;
                int col = c * CHUNK + cg * 4 + q;
                lcol = (ee == 1.0f) ? min(lcol, col) : lcol;
            }
        // first-index argmax via ballots: lowest cg holding a half-0
        // candidate wins (cols ascend with cg), else lowest cg with any.
        unsigned long long b0 = __ballot(lcol < CHUNK);
        unsigned long long ba = __ballot(lcol < 1024);
        int srcl = (int)(b0 ? __ffsll(b0) : __ffsll(ba)) - 1;
        int bc = __shfl(lcol, srcl, 64);

        s = __fadd_rn(s, dpp_xor1(s));
        s = __fadd_rn(s, dpp_xor2(s));
        s = __fadd_rn(s, __shfl_xor(s,  4, 64));
        s = __fadd_rn(s, __shfl_xor(s,  8, 64));
        s = __fadd_rn(s, __shfl_xor(s, 16, 64));
        s = __fadd_rn(s, __shfl_xor(s, 32, 64));

        float invS = 1.0f / s;
#pragma unroll
        for (int c = 0; c < NCHUNK; ++c)
#pragma unroll
            for (int q = 0; q < 4; ++q)
                likpart[c][q] = fmaf(acc[c][r][q], invS, likpart[c][q]);

        // hard-gather write: quantize[row][cg] = embedT[bc][cg]
        // nontemporal: avoid write-allocate RFO on the 64 MB output
        int row = rowbase + r;
        __builtin_nontemporal_store(embedT[bc * DIMS + cg],
                                    &out[(size_t)row * DIMS + cg]);
    }

    // ---- block-level likelihood reduction (reuse e_lds) ----
    float* red = e_lds;
    __syncthreads();
    red[tid] = 0.0f;
    __syncthreads();
#pragma unroll
    for (int c = 0; c < NCHUNK; ++c)
#pragma unroll
        for (int q = 0; q < 4; ++q)
            atomicAdd(&red[c * CHUNK + cg * 4 + q], likpart[c][q]);
    __syncthreads();
    atomicAdd(&lik[tid], red[tid]);
}

// ---------------------------------------------------------------------------
// finish: likelihoods = lik_sum / N; quant_loss = 0.25 * mean(p*(log p - log(l+eps)))
// ---------------------------------------------------------------------------
__global__ void finish_kernel(const float* __restrict__ lik,
                              float* __restrict__ out) {
    int tid = threadIdx.x;   // 512 threads
    float l = lik[tid] / 262144.0f;     // exact: divide by 2^18
    out[16777217 + tid] = l;
    const float p = 1.0f / 512.0f;
    float term = __fmul_rn(p, __fsub_rn(logf(p), logf(l + 1e-10f)));
#pragma unroll
    for (int mask = 1; mask < 64; mask <<= 1)
        term += __shfl_xor(term, mask, 64);
    __shared__ float ws[8];
    if ((tid & 63) == 0) ws[tid >> 6] = term;
    __syncthreads();
    if (tid == 0) {
        float ssum = 0.0f;
        for (int i = 0; i < 8; ++i) ssum += ws[i];
        out[16777216] = 0.25f * (ssum / 512.0f);
    }
}

extern "C" void kernel_launch(void* const* d_in, const int* in_sizes, int n_in,
                              void* d_out, int out_size, void* d_ws, size_t ws_size,
                              hipStream_t stream) {
    const float* x     = (const float*)d_in[0];
    const float* embed = (const float*)d_in[1];
    const float* sigma = (const float*)d_in[2];
    float* out = (float*)d_out;
    float* ws  = (float*)d_ws;

    float* embedT = ws;             // 512*64 = 32768 floats
    float* enorm  = ws + 32768;     // 512 floats
    float* lik    = ws + 33280;     // 512 floats

    prep_kernel<<<KCODES, DIMS, 0, stream>>>(embed, embedT, enorm, lik);
    main_kernel<<<NROWS / MTILE, NTHREADS, 0, stream>>>(x, embed, sigma,
                                                        embedT, enorm, lik, out);
    finish_kernel<<<1, NTHREADS, 0, stream>>>(lik, out);
}